// Round 1
// baseline (482.808 us; speedup 1.0000x reference)
//
#include <hip/hip_runtime.h>

#define N_ 65536
#define D_ 768
#define L_ 100
#define B_ 8192

#define A2_BLK (L_ * D_ / 4)   // 19200 blocks, 4 waves each: one (q,d) per wave
#define W2_BLK (D_ / 2)        // 384 blocks: 2 rows of W2 each
#define OFF_BLK (B_ / 256)     // 32 blocks: bag start offsets via binary search

// ---- prep: Att2 = att @ W_fc^T, W2 = W_fc @ W_cls, c = att@b_fc, b2 = b_fc@W_cls,
// ----       off[b] = lower_bound(seg, b)  (hoisted out of the per-bag kernels)
__device__ __forceinline__ int lower_bound_seg(const int* __restrict__ seg, int key) {
    int lo = 0, hi = N_;
    while (lo < hi) {
        int mid = (lo + hi) >> 1;
        if (seg[mid] < key) lo = mid + 1; else hi = mid;
    }
    return lo;
}

__global__ __launch_bounds__(256) void prep_kernel(
    const float* __restrict__ Wfc,  const float* __restrict__ att,
    const float* __restrict__ Wcls, const float* __restrict__ bfc,
    const int*   __restrict__ seg,
    float* __restrict__ Att2, float* __restrict__ W2,
    float* __restrict__ cq,   float* __restrict__ b2,
    int*   __restrict__ off)
{
    int bid = blockIdx.x;
    if (bid < A2_BLK) {
        // Att2[q][d] = dot(W_fc row d, att row q) — one wave per (q,d)
        int gw   = bid * 4 + (threadIdx.x >> 6);
        int lane = threadIdx.x & 63;
        int q = gw / D_, d = gw % D_;
        const float4* wr = (const float4*)(Wfc + (size_t)d * D_);
        const float4* ar = (const float4*)(att + (size_t)q * D_);
        float s = 0.f;
#pragma unroll
        for (int jj = 0; jj < 3; ++jj) {
            float4 w4 = wr[lane + jj * 64];
            float4 a4 = ar[lane + jj * 64];
            s += w4.x * a4.x + w4.y * a4.y + w4.z * a4.z + w4.w * a4.w;
        }
#pragma unroll
        for (int o = 32; o > 0; o >>= 1) s += __shfl_xor(s, o, 64);
        if (lane == 0) Att2[(size_t)q * D_ + d] = s;
    } else if (bid < A2_BLK + W2_BLK) {
        // W2[d][l] = dot(W_fc row d, W_cls col l) — 2 d-rows per block
        __shared__ float wf[2 * D_];
        int bb = bid - A2_BLK;
        for (int t = threadIdx.x; t < 2 * D_; t += 256)
            wf[t] = Wfc[(size_t)(bb * 2) * D_ + t];
        __syncthreads();
        int l  = threadIdx.x & 127;
        int dh = threadIdx.x >> 7;
        if (l < L_) {
            float s = 0.f;
#pragma unroll 4
            for (int j = 0; j < D_; ++j)
                s += wf[dh * D_ + j] * Wcls[j * L_ + l];
            W2[(size_t)(bb * 2 + dh) * L_ + l] = s;
        }
    } else if (bid == A2_BLK + W2_BLK) {
        // c[q] = att[q]·b_fc ; b2[l] = b_fc·W_cls[:,l]
        int t = threadIdx.x;
        if (t < L_) {
            float s = 0.f;
#pragma unroll 4
            for (int j = 0; j < D_; ++j) s += att[(size_t)t * D_ + j] * bfc[j];
            cq[t] = s;
        } else if (t < 2 * L_) {
            int l = t - L_;
            float s = 0.f;
#pragma unroll 4
            for (int j = 0; j < D_; ++j) s += bfc[j] * Wcls[j * L_ + l];
            b2[l] = s;
        }
    } else {
        // off[b] table (one binary search per bag, done once)
        int b = (bid - (A2_BLK + W2_BLK + 1)) * 256 + threadIdx.x;
        off[b] = lower_bound_seg(seg, b);
        if (b == 0) off[B_] = N_;
    }
}

// ---- pass L: logit[i] = dot(h[i], Att2[query[i]]) + cq[query[i]] ------------
// One wave per row: 65536 independent waves, pure streaming read of H.
__global__ __launch_bounds__(256) void logit_kernel(
    const float* __restrict__ H, const float* __restrict__ Att2,
    const float* __restrict__ cq, const int* __restrict__ query,
    float* __restrict__ logit)
{
    int wv   = threadIdx.x >> 6;
    int lane = threadIdx.x & 63;
    int i    = blockIdx.x * 4 + wv;
    int q    = query[i];
    const float4* hr = (const float4*)(H + (size_t)i * D_);
    const float4* ar = (const float4*)(Att2 + (size_t)q * D_);
    float d = 0.f;
#pragma unroll
    for (int jj = 0; jj < 3; ++jj) {
        float4 h4 = hr[lane + jj * 64];
        float4 a4 = ar[lane + jj * 64];
        d += h4.x * a4.x + h4.y * a4.y + h4.z * a4.z + h4.w * a4.w;
    }
#pragma unroll
    for (int o = 32; o > 0; o >>= 1) d += __shfl_xor(d, o, 64);
    if (lane == 0) logit[i] = d + cq[q];
}

// ---- pass S: exact softmax over bag logits + weighted row sum ---------------
// One wave per bag. Softmax over <=64 logits lane-parallel (2 shuffle reduces
// total). Weighted-sum loop has NO serial dependence: every H load is
// independent of the accumulator, so loads pipeline freely.
__global__ __launch_bounds__(256) void bag_kernel(
    const float* __restrict__ H, const float* __restrict__ logit,
    const int* __restrict__ off,
    float* __restrict__ hbar, float* __restrict__ sflag)
{
    int wv   = threadIdx.x >> 6;
    int b    = blockIdx.x * 4 + wv;
    int lane = threadIdx.x & 63;

    int s = off[b], e = off[b + 1];

    float acc[12];
#pragma unroll
    for (int j = 0; j < 12; ++j) acc[j] = 0.f;

    if (e > s) {
        // lane-parallel max
        float lm = -INFINITY;
        for (int i = s + lane; i < e; i += 64) lm = fmaxf(lm, logit[i]);
#pragma unroll
        for (int o = 32; o > 0; o >>= 1) lm = fmaxf(lm, __shfl_xor(lm, o, 64));
        // lane-parallel sum of exp
        float ls = 0.f;
        for (int i = s + lane; i < e; i += 64) ls += __expf(logit[i] - lm);
#pragma unroll
        for (int o = 32; o > 0; o >>= 1) ls += __shfl_xor(ls, o, 64);
        float invz = 1.f / ls;

        // weighted sum: wgt is wave-uniform (broadcast logit load + 1 exp/row)
        for (int i = s; i < e; ++i) {
            float wgt = __expf(logit[i] - lm) * invz;
            const float4* hr = (const float4*)(H + (size_t)i * D_);
#pragma unroll
            for (int jj = 0; jj < 3; ++jj) {
                float4 h4 = hr[lane + jj * 64];
                acc[jj*4+0] += wgt * h4.x;
                acc[jj*4+1] += wgt * h4.y;
                acc[jj*4+2] += wgt * h4.z;
                acc[jj*4+3] += wgt * h4.w;
            }
        }
    }

    float4* o4 = (float4*)(hbar + (size_t)b * D_);
#pragma unroll
    for (int jj = 0; jj < 3; ++jj)
        o4[lane + jj * 64] = make_float4(acc[jj*4+0], acc[jj*4+1],
                                         acc[jj*4+2], acc[jj*4+3]);
    if (lane == 0) sflag[b] = (e > s) ? 1.f : 0.f;
}

// ---- out = hbar @ W2 + sflag*b2 + b_cls  (8 bags / block, 256 threads) ------
__global__ __launch_bounds__(256) void cls_kernel(
    const float* __restrict__ hbar, const float* __restrict__ W2,
    const float* __restrict__ b2,   const float* __restrict__ bcls,
    const float* __restrict__ sflag, float* __restrict__ out)
{
    __shared__ float sm[8 * D_];                 // 24 KB
    int b0  = blockIdx.x * 8;
    int tid = threadIdx.x;
    const float4* src = (const float4*)(hbar + (size_t)b0 * D_);
    float4* dst = (float4*)sm;
#pragma unroll
    for (int j = 0; j < 6; ++j) dst[tid + j * 256] = src[tid + j * 256];
    __syncthreads();

    int g = tid >> 7;                            // bag half: 0 -> bags 0..3, 1 -> 4..7
    int l = tid & 127;
    if (l < L_) {
        float acc[4];
#pragma unroll
        for (int j = 0; j < 4; ++j) acc[j] = 0.f;
        const float* smg = sm + g * 4 * D_;
#pragma unroll 4
        for (int d = 0; d < D_; ++d) {
            float wv = W2[d * L_ + l];
#pragma unroll
            for (int j = 0; j < 4; ++j) acc[j] += smg[j * D_ + d] * wv;
        }
        float bb = bcls[l], b2v = b2[l];
#pragma unroll
        for (int j = 0; j < 4; ++j) {
            int b = b0 + g * 4 + j;
            out[(size_t)b * L_ + l] = acc[j] + sflag[b] * b2v + bb;
        }
    }
}

extern "C" void kernel_launch(void* const* d_in, const int* in_sizes, int n_in,
                              void* d_out, int out_size, void* d_ws, size_t ws_size,
                              hipStream_t stream) {
    const float* h    = (const float*)d_in[0];
    const float* Wfc  = (const float*)d_in[1];
    const float* bfc  = (const float*)d_in[2];
    const float* att  = (const float*)d_in[3];
    const float* Wcls = (const float*)d_in[4];
    const float* bcls = (const float*)d_in[5];
    const int*   query= (const int*)d_in[6];
    const int*   seg  = (const int*)d_in[7];
    float* out = (float*)d_out;

    char* w = (char*)d_ws;
    float* Att2  = (float*)w;  w += (size_t)L_ * D_ * 4;
    float* W2    = (float*)w;  w += (size_t)D_ * L_ * 4;
    float* cq    = (float*)w;  w += 128 * 4;
    float* b2    = (float*)w;  w += 128 * 4;
    float* sflag = (float*)w;  w += (size_t)B_ * 4;
    float* logit = (float*)w;  w += (size_t)N_ * 4;
    int*   off   = (int*)w;    w += (size_t)(B_ + 128) * 4;
    float* hbar  = (float*)w;  // B_*D_*4 = 25 MB

    prep_kernel<<<A2_BLK + W2_BLK + 1 + OFF_BLK, 256, 0, stream>>>(
        Wfc, att, Wcls, bfc, seg, Att2, W2, cq, b2, off);
    logit_kernel<<<N_ / 4, 256, 0, stream>>>(h, Att2, cq, query, logit);
    bag_kernel <<<B_ / 4, 256, 0, stream>>>(h, logit, off, hbar, sflag);
    cls_kernel <<<B_ / 8, 256, 0, stream>>>(hbar, W2, b2, bcls, sflag, out);
}

// Round 2
// 450.812 us; speedup vs baseline: 1.0710x; 1.0710x over previous
//
#include <hip/hip_runtime.h>

#define N_ 65536
#define D_ 768
#define L_ 100
#define B_ 8192

// ---- prep grid layout -------------------------------------------------------
#define AT_QT 25                    // q-tiles of 4 (100/4)
#define AT_DT 192                   // d-tiles of 4 (768/4)
#define AT_BLK ((AT_QT * AT_DT) / 4)  // 1200 blocks, 4 waves, wave = 4x4 tile
#define W2B (D_ / 2)                // 384 blocks: 2 rows of W2 each
#define CQB (L_ / 4)                // 25 blocks: wave per q for cq
#define OFFB 32                     // 8192 binary searches
#define PREP_BLK (AT_BLK + W2B + CQB + 1 + OFFB)  // 1642

__device__ __forceinline__ int lower_bound_seg(const int* __restrict__ seg, int key) {
    int lo = 0, hi = N_;
    while (lo < hi) {
        int mid = (lo + hi) >> 1;
        if (seg[mid] < key) lo = mid + 1; else hi = mid;
    }
    return lo;
}

// Att2 = att @ Wfc^T ; W2 = Wfc @ Wcls ; cq = att@bfc ; b2 = bfc@Wcls ; off[]
__global__ __launch_bounds__(256) void prep_kernel(
    const float* __restrict__ Wfc,  const float* __restrict__ att,
    const float* __restrict__ Wcls, const float* __restrict__ bfc,
    const int*   __restrict__ seg,
    float* __restrict__ Att2, float* __restrict__ W2,
    float* __restrict__ cq,   float* __restrict__ b2,
    int*   __restrict__ off)
{
    int bid  = blockIdx.x;
    int wv   = threadIdx.x >> 6;
    int lane = threadIdx.x & 63;

    if (bid < AT_BLK) {
        // wave computes a 4q x 4d tile of Att2 via outer product, k split over lanes
        int t  = bid * 4 + wv;
        int q0 = (t / AT_DT) * 4;
        int d0 = (t % AT_DT) * 4;
        const float4* at4 = (const float4*)att;
        const float4* wf4 = (const float4*)Wfc;
        float acc[4][4];
#pragma unroll
        for (int qi = 0; qi < 4; ++qi)
#pragma unroll
            for (int di = 0; di < 4; ++di) acc[qi][di] = 0.f;
#pragma unroll
        for (int jj = 0; jj < 3; ++jj) {
            float4 av[4], wv4[4];
#pragma unroll
            for (int r = 0; r < 4; ++r) av[r]  = at4[(size_t)(q0 + r) * 192 + lane + jj * 64];
#pragma unroll
            for (int r = 0; r < 4; ++r) wv4[r] = wf4[(size_t)(d0 + r) * 192 + lane + jj * 64];
#pragma unroll
            for (int qi = 0; qi < 4; ++qi)
#pragma unroll
                for (int di = 0; di < 4; ++di)
                    acc[qi][di] += av[qi].x * wv4[di].x + av[qi].y * wv4[di].y
                                 + av[qi].z * wv4[di].z + av[qi].w * wv4[di].w;
        }
#pragma unroll
        for (int qi = 0; qi < 4; ++qi)
#pragma unroll
            for (int di = 0; di < 4; ++di) {
                float s = acc[qi][di];
#pragma unroll
                for (int o = 32; o > 0; o >>= 1) s += __shfl_xor(s, o, 64);
                acc[qi][di] = s;
            }
        if (lane == 0) {
#pragma unroll
            for (int qi = 0; qi < 4; ++qi)
                *(float4*)(Att2 + (size_t)(q0 + qi) * D_ + d0) =
                    make_float4(acc[qi][0], acc[qi][1], acc[qi][2], acc[qi][3]);
        }
    } else if (bid < AT_BLK + W2B) {
        // W2[d][l] = Wfc row d (scalar loads) . Wcls[:,l] (vector loads)
        int bb = bid - AT_BLK;
        int dh = __builtin_amdgcn_readfirstlane(threadIdx.x >> 7);
        int l  = threadIdx.x & 127;
        int d  = bb * 2 + dh;
        const float* wr = Wfc + (size_t)d * D_;
        if (l < L_) {
            float s = 0.f;
#pragma unroll 4
            for (int j = 0; j < D_; ++j)
                s = fmaf(wr[j], Wcls[(size_t)j * L_ + l], s);
            W2[(size_t)d * L_ + l] = s;
        }
    } else if (bid < AT_BLK + W2B + CQB) {
        // cq[q] = att[q] . bfc  — one wave per q, coalesced dot
        int q = (bid - (AT_BLK + W2B)) * 4 + wv;
        const float4* ar = (const float4*)(att + (size_t)q * D_);
        const float4* br = (const float4*)bfc;
        float s = 0.f;
#pragma unroll
        for (int jj = 0; jj < 3; ++jj) {
            float4 a4 = ar[lane + jj * 64];
            float4 b4 = br[lane + jj * 64];
            s += a4.x * b4.x + a4.y * b4.y + a4.z * b4.z + a4.w * b4.w;
        }
#pragma unroll
        for (int o = 32; o > 0; o >>= 1) s += __shfl_xor(s, o, 64);
        if (lane == 0) cq[q] = s;
    } else if (bid == AT_BLK + W2B + CQB) {
        // b2[l] = bfc . Wcls[:,l]
        int l = threadIdx.x;
        if (l < L_) {
            float s = 0.f;
#pragma unroll 4
            for (int j = 0; j < D_; ++j)
                s = fmaf(bfc[j], Wcls[(size_t)j * L_ + l], s);
            b2[l] = s;
        }
    } else {
        // off[b] table
        int b = (bid - (AT_BLK + W2B + CQB + 1)) * 256 + threadIdx.x;
        off[b] = lower_bound_seg(seg, b);
        if (b == 0) off[B_] = N_;
    }
}

// ---- fused bag kernel: dots -> softmax -> weighted sum, one wave per bag ----
// Pass A reads H from HBM; pass C re-reads the SAME rows just touched by this
// CU (<=24 KB/bag) -> mostly L1/L2 hits. Logits parked in per-wave LDS.
__global__ __launch_bounds__(256) void bag_kernel(
    const float* __restrict__ H, const float* __restrict__ Att2,
    const float* __restrict__ cq, const int* __restrict__ query,
    const int* __restrict__ off,
    float* __restrict__ hbar, float* __restrict__ sflag)
{
    __shared__ float smL[4][512];
    int wv   = threadIdx.x >> 6;
    int lane = threadIdx.x & 63;
    int b    = blockIdx.x * 4 + wv;
    int s    = off[b], e = off[b + 1];
    int n    = e - s;
    if (n > 512) n = 512;               // Binomial(65536,1/8192): P(n>512)=0
    float* mL = smL[wv];

    // ---- pass A: logits (2-row unroll for load pipelining) ----
    int r = 0;
    for (; r + 2 <= n; r += 2) {
        int i0 = s + r, i1 = i0 + 1;
        int q0 = query[i0], q1 = query[i1];
        const float4* h0 = (const float4*)(H    + (size_t)i0 * D_);
        const float4* h1 = (const float4*)(H    + (size_t)i1 * D_);
        const float4* a0 = (const float4*)(Att2 + (size_t)q0 * D_);
        const float4* a1 = (const float4*)(Att2 + (size_t)q1 * D_);
        float d0 = 0.f, d1 = 0.f;
#pragma unroll
        for (int jj = 0; jj < 3; ++jj) {
            float4 x0 = h0[lane + jj * 64], y0 = a0[lane + jj * 64];
            float4 x1 = h1[lane + jj * 64], y1 = a1[lane + jj * 64];
            d0 += x0.x * y0.x + x0.y * y0.y + x0.z * y0.z + x0.w * y0.w;
            d1 += x1.x * y1.x + x1.y * y1.y + x1.z * y1.z + x1.w * y1.w;
        }
#pragma unroll
        for (int o = 32; o > 0; o >>= 1) {
            d0 += __shfl_xor(d0, o, 64);
            d1 += __shfl_xor(d1, o, 64);
        }
        if (lane == 0) { mL[r] = d0 + cq[q0]; mL[r + 1] = d1 + cq[q1]; }
    }
    if (r < n) {
        int i0 = s + r;
        int q0 = query[i0];
        const float4* h0 = (const float4*)(H    + (size_t)i0 * D_);
        const float4* a0 = (const float4*)(Att2 + (size_t)q0 * D_);
        float d0 = 0.f;
#pragma unroll
        for (int jj = 0; jj < 3; ++jj) {
            float4 x0 = h0[lane + jj * 64], y0 = a0[lane + jj * 64];
            d0 += x0.x * y0.x + x0.y * y0.y + x0.z * y0.z + x0.w * y0.w;
        }
#pragma unroll
        for (int o = 32; o > 0; o >>= 1) d0 += __shfl_xor(d0, o, 64);
        if (lane == 0) mL[r] = d0 + cq[q0];
    }

    // ---- pass B: exact softmax over mL[0..n) (lane-parallel) ----
    float lm = -INFINITY;
    for (int k = lane; k < n; k += 64) lm = fmaxf(lm, mL[k]);
#pragma unroll
    for (int o = 32; o > 0; o >>= 1) lm = fmaxf(lm, __shfl_xor(lm, o, 64));
    float ls = 0.f;
    for (int k = lane; k < n; k += 64) {
        float ev = __expf(mL[k] - lm);
        mL[k] = ev;
        ls += ev;
    }
#pragma unroll
    for (int o = 32; o > 0; o >>= 1) ls += __shfl_xor(ls, o, 64);
    float invz = (n > 0) ? 1.f / ls : 0.f;

    // ---- pass C: weighted row sum (rows are L1/L2-hot) ----
    float acc[12];
#pragma unroll
    for (int j = 0; j < 12; ++j) acc[j] = 0.f;
    r = 0;
    for (; r + 2 <= n; r += 2) {
        float w0 = mL[r] * invz, w1 = mL[r + 1] * invz;
        const float4* h0 = (const float4*)(H + (size_t)(s + r)     * D_);
        const float4* h1 = (const float4*)(H + (size_t)(s + r + 1) * D_);
#pragma unroll
        for (int jj = 0; jj < 3; ++jj) {
            float4 x0 = h0[lane + jj * 64], x1 = h1[lane + jj * 64];
            acc[jj*4+0] += w0 * x0.x + w1 * x1.x;
            acc[jj*4+1] += w0 * x0.y + w1 * x1.y;
            acc[jj*4+2] += w0 * x0.z + w1 * x1.z;
            acc[jj*4+3] += w0 * x0.w + w1 * x1.w;
        }
    }
    if (r < n) {
        float w0 = mL[r] * invz;
        const float4* h0 = (const float4*)(H + (size_t)(s + r) * D_);
#pragma unroll
        for (int jj = 0; jj < 3; ++jj) {
            float4 x0 = h0[lane + jj * 64];
            acc[jj*4+0] += w0 * x0.x;
            acc[jj*4+1] += w0 * x0.y;
            acc[jj*4+2] += w0 * x0.z;
            acc[jj*4+3] += w0 * x0.w;
        }
    }

    float4* o4 = (float4*)(hbar + (size_t)b * D_);
#pragma unroll
    for (int jj = 0; jj < 3; ++jj)
        o4[lane + jj * 64] = make_float4(acc[jj*4+0], acc[jj*4+1],
                                         acc[jj*4+2], acc[jj*4+3]);
    if (lane == 0) sflag[b] = (n > 0) ? 1.f : 0.f;
}

// ---- out = hbar @ W2 + sflag*b2 + b_cls -------------------------------------
// hbar via wave-uniform SCALAR loads (SMEM pipe), W2 via coalesced vector loads.
__global__ __launch_bounds__(256) void cls_kernel(
    const float* __restrict__ hbar, const float* __restrict__ W2,
    const float* __restrict__ b2,   const float* __restrict__ bcls,
    const float* __restrict__ sflag, float* __restrict__ out)
{
    int tid = threadIdx.x;
    int g   = __builtin_amdgcn_readfirstlane(tid >> 7);  // wave-uniform bag half
    int l   = tid & 127;
    int b0  = blockIdx.x * 8 + g * 4;
    const float* hb = hbar + (size_t)b0 * D_;

    if (l < L_) {
        float a0 = 0.f, a1 = 0.f, a2 = 0.f, a3 = 0.f;
#pragma unroll 4
        for (int d = 0; d < D_; ++d) {
            float w = W2[(size_t)d * L_ + l];
            a0 = fmaf(hb[d],          w, a0);
            a1 = fmaf(hb[D_ + d],     w, a1);
            a2 = fmaf(hb[2 * D_ + d], w, a2);
            a3 = fmaf(hb[3 * D_ + d], w, a3);
        }
        float bb = bcls[l], b2v = b2[l];
        out[(size_t)(b0 + 0) * L_ + l] = a0 + sflag[b0 + 0] * b2v + bb;
        out[(size_t)(b0 + 1) * L_ + l] = a1 + sflag[b0 + 1] * b2v + bb;
        out[(size_t)(b0 + 2) * L_ + l] = a2 + sflag[b0 + 2] * b2v + bb;
        out[(size_t)(b0 + 3) * L_ + l] = a3 + sflag[b0 + 3] * b2v + bb;
    }
}

extern "C" void kernel_launch(void* const* d_in, const int* in_sizes, int n_in,
                              void* d_out, int out_size, void* d_ws, size_t ws_size,
                              hipStream_t stream) {
    const float* h    = (const float*)d_in[0];
    const float* Wfc  = (const float*)d_in[1];
    const float* bfc  = (const float*)d_in[2];
    const float* att  = (const float*)d_in[3];
    const float* Wcls = (const float*)d_in[4];
    const float* bcls = (const float*)d_in[5];
    const int*   query= (const int*)d_in[6];
    const int*   seg  = (const int*)d_in[7];
    float* out = (float*)d_out;

    char* w = (char*)d_ws;
    float* Att2  = (float*)w;  w += (size_t)L_ * D_ * 4;
    float* W2    = (float*)w;  w += (size_t)D_ * L_ * 4;
    float* cq    = (float*)w;  w += 128 * 4;
    float* b2    = (float*)w;  w += 128 * 4;
    float* sflag = (float*)w;  w += (size_t)B_ * 4;
    int*   off   = (int*)w;    w += (size_t)(B_ + 128) * 4;
    float* hbar  = (float*)w;  // B_*D_*4 = 25 MB

    prep_kernel<<<PREP_BLK, 256, 0, stream>>>(
        Wfc, att, Wcls, bfc, seg, Att2, W2, cq, b2, off);
    bag_kernel <<<B_ / 4, 256, 0, stream>>>(h, Att2, cq, query, off, hbar, sflag);
    cls_kernel <<<B_ / 8, 256, 0, stream>>>(hbar, W2, b2, bcls, sflag, out);
}